// Round 9
// baseline (311.778 us; speedup 1.0000x reference)
//
#include <hip/hip_runtime.h>
#include <hip/hip_bf16.h>
#include <math.h>

// Problem constants (fixed by the reference):
// N=20000, E=320000, DIN=128, DH=64, H=8, B=16, C=10, NEG_SLOPE=0.2
// Key identity exploited: GAT is linear in features ->
//   out[n][head] = (sum_e alpha_e * h[src_e]) @ W_head
// so we aggregate the 64-dim h (2.56MB bf16 table, single-XCD-L2 resident)
// instead of the 512-dim feat, then apply W once per layer via MFMA.

#define NEG_SLOPE 0.2f

typedef float f32x4 __attribute__((ext_vector_type(4)));
typedef short bf16x8 __attribute__((ext_vector_type(8)));

__device__ __forceinline__ float bf2f(__hip_bfloat16 b) { return __bfloat162float(b); }
__device__ __forceinline__ unsigned short f2bfu(float x) {
    __hip_bfloat16 b = __float2bfloat16(x);
    return *(unsigned short*)&b;
}
__device__ __forceinline__ void unpack8_bf16(uint4 u, float* f) {
    f[0] = __uint_as_float(u.x << 16);
    f[1] = __uint_as_float(u.x & 0xffff0000u);
    f[2] = __uint_as_float(u.y << 16);
    f[3] = __uint_as_float(u.y & 0xffff0000u);
    f[4] = __uint_as_float(u.z << 16);
    f[5] = __uint_as_float(u.z & 0xffff0000u);
    f[6] = __uint_as_float(u.w << 16);
    f[7] = __uint_as_float(u.w & 0xffff0000u);
}

// ---------------- CSR build ----------------
__global__ void hist_kernel(const int* __restrict__ dst, int* __restrict__ cnt, int E) {
    int e = blockIdx.x * 256 + threadIdx.x;
    if (e < E) atomicAdd(&cnt[dst[e]], 1);
}

__global__ __launch_bounds__(1024) void scan_kernel(const int* __restrict__ cnt,
                                                    int* __restrict__ row_start,
                                                    int* __restrict__ cursor, int N) {
    __shared__ int part[1024];
    int t = threadIdx.x;
    int CH = (N + 1023) >> 10;
    int beg = t * CH;
    int end = beg + CH; if (end > N) end = N;
    if (beg > N) beg = N;
    int local = 0;
    for (int i = beg; i < end; ++i) local += cnt[i];
    part[t] = local;
    __syncthreads();
    for (int off = 1; off < 1024; off <<= 1) {
        int v = (t >= off) ? part[t - off] : 0;
        __syncthreads();
        part[t] += v;
        __syncthreads();
    }
    int run = part[t] - local;   // exclusive prefix
    for (int i = beg; i < end; ++i) {
        row_start[i] = run; cursor[i] = run;
        run += cnt[i];
    }
    if (t == 1023) row_start[N] = run;   // == E
}

__global__ void scatter_kernel(const int* __restrict__ src, const int* __restrict__ dst,
                               int* __restrict__ cursor, int* __restrict__ src_sorted, int E) {
    int e = blockIdx.x * 256 + threadIdx.x;
    if (e < E) {
        int p = atomicAdd(&cursor[dst[e]], 1);
        src_sorted[p] = src[e];
    }
}

// ---------------- wprep: wl[k][h] = sum_d W[k][h*64+d]*al[h][d]; biasm[d] = mean_h bias[h][d] ---
__global__ __launch_bounds__(256) void wprep_kernel(const float* __restrict__ W,
                                                    const float* __restrict__ al,
                                                    const float* __restrict__ ar,
                                                    const float* __restrict__ bias,
                                                    float* __restrict__ wl, float* __restrict__ wr,
                                                    float* __restrict__ biasm) {
    int t = threadIdx.x;
    for (int i = t; i < 512; i += 256) {
        int k = i >> 3, h = i & 7;
        float sl = 0.f, sr = 0.f;
#pragma unroll 8
        for (int d = 0; d < 64; ++d) {
            float wv = W[k * 512 + h * 64 + d];
            sl = fmaf(wv, al[h * 64 + d], sl);
            sr = fmaf(wv, ar[h * 64 + d], sr);
        }
        wl[i] = sl; wr[i] = sr;          // layout [k][h] == k*8+h
    }
    if (t < 64) {
        float s = 0.f;
#pragma unroll
        for (int h = 0; h < 8; ++h) s += bias[h * 64 + t];
        biasm[t] = 0.125f * s;
    }
}

// ---------------- wswizB: B[K=h*64+k][d] = W[k][h*64+d] -> bf16 MFMA B-fragments ----------
// frag fid = (ctg*16 + ks)*64 + lane; value j: K = ks*32 + (lane>>4)*8 + j, d = ctg*16 + (lane&15)
__global__ __launch_bounds__(256) void wswizB_kernel(const float* __restrict__ W,
                                                     unsigned short* __restrict__ Bz) {
    int fid = blockIdx.x * 256 + threadIdx.x;   // 0..4095
    int lane = fid & 63;
    int ks = (fid >> 6) & 15;
    int ctg = fid >> 10;                         // 0..3
    int d = ctg * 16 + (lane & 15);
    int K0 = ks * 32 + ((lane >> 4) << 3);
    unsigned short v[8];
#pragma unroll
    for (int j = 0; j < 8; ++j) {
        int K = K0 + j;
        v[j] = f2bfu(W[(K & 63) * 512 + (K >> 6) * 64 + d]);
    }
    ushort4* dst = (ushort4*)(Bz + (size_t)fid * 8);
    dst[0] = make_ushort4(v[0], v[1], v[2], v[3]);
    dst[1] = make_ushort4(v[4], v[5], v[6], v[7]);
}

// ---------------- input GEMM + fused el/er: h0 = bf16(g @ W_in + b_in) ----------------
__global__ __launch_bounds__(256) void in_gemm(const float* __restrict__ g,
                                               const float* __restrict__ W,
                                               const float* __restrict__ b,
                                               const float* __restrict__ wl,
                                               const float* __restrict__ wr,
                                               unsigned short* __restrict__ h0,
                                               unsigned short* __restrict__ el,
                                               unsigned short* __restrict__ er, int N) {
    __shared__ float gt[128][36];   // gt[k][r]
    __shared__ float sh[32][65];    // h0 tile for elr epilogue (pad 65: conflict-free col reads)
    int t = threadIdx.x;
    int n0 = blockIdx.x * 32;
#pragma unroll
    for (int i = 0; i < 4; ++i) {
        int ch = t + i * 256;
        int r = ch >> 5, k0 = (ch & 31) << 2;
        float4 v = (n0 + r < N) ? *(const float4*)(g + (size_t)(n0 + r) * 128 + k0)
                                : make_float4(0.f, 0.f, 0.f, 0.f);
        gt[k0 + 0][r] = v.x; gt[k0 + 1][r] = v.y; gt[k0 + 2][r] = v.z; gt[k0 + 3][r] = v.w;
    }
    __syncthreads();
    int c = t & 63, rg = t >> 6;
    float acc[8];
#pragma unroll
    for (int j = 0; j < 8; ++j) acc[j] = 0.f;
#pragma unroll 4
    for (int k = 0; k < 128; ++k) {
        float w = W[k * 64 + c];
        const float* hp = &gt[k][rg * 8];
        float4 ha = *(const float4*)hp;
        float4 hb = *(const float4*)(hp + 4);
        acc[0] = fmaf(ha.x, w, acc[0]);
        acc[1] = fmaf(ha.y, w, acc[1]);
        acc[2] = fmaf(ha.z, w, acc[2]);
        acc[3] = fmaf(ha.w, w, acc[3]);
        acc[4] = fmaf(hb.x, w, acc[4]);
        acc[5] = fmaf(hb.y, w, acc[5]);
        acc[6] = fmaf(hb.z, w, acc[6]);
        acc[7] = fmaf(hb.w, w, acc[7]);
    }
    float bb = b[c];
#pragma unroll
    for (int j = 0; j < 8; ++j) {
        int r = rg * 8 + j;
        float v = acc[j] + bb;
        sh[r][c] = v;
        if (n0 + r < N) h0[(size_t)(n0 + r) * 64 + c] = f2bfu(v);
    }
    __syncthreads();
    // fused el/er: thread (r = t>>3, h = t&7)
    int r = t >> 3, hh = t & 7;
    float sl = 0.f, sr = 0.f;
#pragma unroll 8
    for (int k = 0; k < 64; ++k) {
        float hv = sh[r][k];
        sl = fmaf(hv, wl[k * 8 + hh], sl);
        sr = fmaf(hv, wr[k * 8 + hh], sr);
    }
    if (n0 + r < N) {
        el[(size_t)(n0 + r) * 8 + hh] = f2bfu(sl);
        er[(size_t)(n0 + r) * 8 + hh] = f2bfu(sr);
    }
}

// ---------------- GAT aggregation over h (64-dim, bf16, L2-resident table) --------------
// One wave per node. lane: head h = lane>>3, dims dg = lane&7 -> h[src][dg*8..+8].
// exp-dedup per 8-edge sub-chunk (R7-validated). Output: aggn[n][h*64+dg*8+j] = acc/den (bf16).
// No bias / relu / head-mean here (they commute into out_gemm).
__global__ __launch_bounds__(256, 8) void gat_h(
    const unsigned short* __restrict__ hbf, const unsigned short* __restrict__ el,
    const unsigned short* __restrict__ er,
    const int* __restrict__ row_start, const int* __restrict__ src_sorted,
    unsigned short* __restrict__ aggn, int N) {
    int lane = threadIdx.x & 63;
    int n = blockIdx.x * 4 + (threadIdx.x >> 6);
    if (n >= N) return;
    int h = lane >> 3;
    int dg = lane & 7;
    float erh = bf2f(*(const __hip_bfloat16*)(er + (size_t)n * 8 + h));
    int row = row_start[n];
    int deg = row_start[n + 1] - row;
    const unsigned short* hl = hbf + dg * 8;    // + s*64

    float acc[8];
#pragma unroll
    for (int j = 0; j < 8; ++j) acc[j] = 0.f;
    float den = 0.f;

    for (int base = 0; base < deg; base += 64) {
        int cnt = min(deg - base, 64);
        int sv = (lane < cnt) ? src_sorted[row + base + lane] : 0;
        int nsub = cnt & ~7;
        int hb = lane & 0x38;
        for (int i0 = 0; i0 < nsub; i0 += 8) {
            // exp-dedup: this lane owns (edge = i0 + (lane&7), head = lane>>3)
            int se = __shfl(sv, i0 + (lane & 7), 64);
            float ve = bf2f(*(const __hip_bfloat16*)(el + (size_t)se * 8 + h)) + erh;
            ve = fmaxf(ve, NEG_SLOPE * ve);
            float am = __expf(ve);
#pragma unroll
            for (int e = 0; e < 8; ++e) {
                float a = __shfl(am, hb | e, 64);
                int s = __shfl(sv, i0 + e, 64);
                uint4 u = *(const uint4*)(hl + (size_t)s * 64);
                den += a;
                float f[8];
                unpack8_bf16(u, f);
#pragma unroll
                for (int j = 0; j < 8; ++j) acc[j] = fmaf(a, f[j], acc[j]);
            }
        }
        for (int i = nsub; i < cnt; ++i) {
            int s = __shfl(sv, i, 64);
            uint4 u = *(const uint4*)(hl + (size_t)s * 64);
            float v = bf2f(*(const __hip_bfloat16*)(el + (size_t)s * 8 + h)) + erh;
            v = fmaxf(v, NEG_SLOPE * v);
            float a = __expf(v);
            den += a;
            float f[8];
            unpack8_bf16(u, f);
#pragma unroll
            for (int j = 0; j < 8; ++j) acc[j] = fmaf(a, f[j], acc[j]);
        }
    }

    float invd = deg > 0 ? 1.f / den : 0.f;
    // aggn[n][h*64 + dg*8 + j] == aggn[n*512 + lane*8 + j]  (coalesced 16B/lane)
    ushort4 s0 = make_ushort4(f2bfu(acc[0] * invd), f2bfu(acc[1] * invd),
                              f2bfu(acc[2] * invd), f2bfu(acc[3] * invd));
    ushort4 s1 = make_ushort4(f2bfu(acc[4] * invd), f2bfu(acc[5] * invd),
                              f2bfu(acc[6] * invd), f2bfu(acc[7] * invd));
    ushort4* op = (ushort4*)(aggn + (size_t)n * 512 + lane * 8);
    op[0] = s0; op[1] = s1;
}

// ---------------- out GEMM (MFMA): hnext = mean_h(aggn @ B) + biasm  [N,512]x[512,64] -----
// 256 thr = 4 waves; wave w covers K-chunk [w*128,(w+1)*128). A-frags direct from global.
// Cross-wave reduce via LDS. LAYER==1: relu + bf16 out + fused el/er. LAYER==2: f32 out.
template <int LAYER>
__global__ __launch_bounds__(256) void out_gemm(const unsigned short* __restrict__ aggn,
                                                const unsigned short* __restrict__ Bz,
                                                const float* __restrict__ biasm,
                                                const float* __restrict__ wl,
                                                const float* __restrict__ wr,
                                                unsigned short* __restrict__ hnext_bf,
                                                float* __restrict__ hnext_f,
                                                unsigned short* __restrict__ el,
                                                unsigned short* __restrict__ er, int N) {
    __shared__ float sred[4][32][65];   // 33.3 KB
    int t = threadIdx.x;
    int n0 = blockIdx.x * 32;
    int lane = t & 63, w = t >> 6;
    int lr = lane & 15, lg = lane >> 4;

    f32x4 acc[2][4];
#pragma unroll
    for (int rt = 0; rt < 2; ++rt)
#pragma unroll
        for (int ct = 0; ct < 4; ++ct) acc[rt][ct] = (f32x4){0.f, 0.f, 0.f, 0.f};

    int r0 = min(n0 + lr, N - 1);
    int r1 = min(n0 + 16 + lr, N - 1);
#pragma unroll
    for (int ks2 = 0; ks2 < 4; ++ks2) {
        int kofs = w * 128 + ks2 * 32 + lg * 8;
        bf16x8 a0 = *(const bf16x8*)(aggn + (size_t)r0 * 512 + kofs);
        bf16x8 a1 = *(const bf16x8*)(aggn + (size_t)r1 * 512 + kofs);
#pragma unroll
        for (int ct = 0; ct < 4; ++ct) {
            int fid = (ct * 16 + (w * 4 + ks2)) * 64 + lane;
            bf16x8 bf = *(const bf16x8*)(Bz + (size_t)fid * 8);
            acc[0][ct] = __builtin_amdgcn_mfma_f32_16x16x32_bf16(a0, bf, acc[0][ct], 0, 0, 0);
            acc[1][ct] = __builtin_amdgcn_mfma_f32_16x16x32_bf16(a1, bf, acc[1][ct], 0, 0, 0);
        }
    }
    // stash partials: D row = rt*16 + lg*4 + j, col = ct*16 + lr
#pragma unroll
    for (int rt = 0; rt < 2; ++rt)
#pragma unroll
        for (int ct = 0; ct < 4; ++ct)
#pragma unroll
            for (int j = 0; j < 4; ++j)
                sred[w][rt * 16 + lg * 4 + j][ct * 16 + lr] = acc[rt][ct][j];
    __syncthreads();

    // reduce + epilogue: thread (row r = t>>3, cols c0 = (t&7)*8 .. +8)
    int r = t >> 3, c0 = (t & 7) * 8;
    float v[8];
#pragma unroll
    for (int j = 0; j < 8; ++j) {
        int c = c0 + j;
        float s = sred[0][r][c] + sred[1][r][c] + sred[2][r][c] + sred[3][r][c];
        v[j] = s * 0.125f + biasm[c];
        if (LAYER == 1) v[j] = fmaxf(v[j], 0.f);
    }
    if (LAYER == 1) {
        if (n0 + r < N) {
            ushort4 u0 = make_ushort4(f2bfu(v[0]), f2bfu(v[1]), f2bfu(v[2]), f2bfu(v[3]));
            ushort4 u1 = make_ushort4(f2bfu(v[4]), f2bfu(v[5]), f2bfu(v[6]), f2bfu(v[7]));
            ushort4* op = (ushort4*)(hnext_bf + (size_t)(n0 + r) * 64 + c0);
            op[0] = u0; op[1] = u1;
        }
        // fused el/er from relu'd rows: re-stage into sred[0]
        __syncthreads();
#pragma unroll
        for (int j = 0; j < 8; ++j) sred[0][r][c0 + j] = v[j];
        __syncthreads();
        int hh = t & 7;
        float sl = 0.f, sr = 0.f;
#pragma unroll 8
        for (int k = 0; k < 64; ++k) {
            float hv = sred[0][r][k];
            sl = fmaf(hv, wl[k * 8 + hh], sl);
            sr = fmaf(hv, wr[k * 8 + hh], sr);
        }
        if (n0 + r < N) {
            el[(size_t)(n0 + r) * 8 + hh] = f2bfu(sl);
            er[(size_t)(n0 + r) * 8 + hh] = f2bfu(sr);
        }
    } else {
        if (n0 + r < N) {
            float4* op = (float4*)(hnext_f + (size_t)(n0 + r) * 64 + c0);
            op[0] = make_float4(v[0], v[1], v[2], v[3]);
            op[1] = make_float4(v[4], v[5], v[6], v[7]);
        }
    }
}

// ---------------- per-graph readout partial sums (nodes sorted by graph id) ----------------
__global__ __launch_bounds__(256) void readout_partial(const float* __restrict__ h2,
                                                       const int* __restrict__ gid,
                                                       float* __restrict__ hg, int N) {
    int c = threadIdx.x & 63;
    int r = threadIdx.x >> 6;
    int n0 = blockIdx.x * 256;
    float sum = 0.f; int cur = -1;
    int nend = n0 + 256; if (nend > N) nend = N;
    for (int n = n0 + r; n < nend; n += 4) {
        int g = gid[n];
        if (g != cur) {
            if (cur >= 0) atomicAdd(&hg[cur * 64 + c], sum);
            cur = g; sum = 0.f;
        }
        sum += h2[(size_t)n * 64 + c];
    }
    if (cur >= 0) atomicAdd(&hg[cur * 64 + c], sum);
}

// ---------------- final head: counts, mean, GEMM 16x64x10, softmax ----------------
__global__ __launch_bounds__(256) void head_kernel(const float* __restrict__ hg_sum,
                                                   const int* __restrict__ gid,
                                                   const float* __restrict__ W_head,
                                                   const float* __restrict__ b_head,
                                                   float* __restrict__ out, int N) {
    __shared__ int scnt[16];
    __shared__ float shg[16 * 64];
    __shared__ float slog[16 * 10];
    int t = threadIdx.x;
    if (t < 16) scnt[t] = 0;
    __syncthreads();
    for (int n = t; n < N; n += 256) atomicAdd(&scnt[gid[n]], 1);
    __syncthreads();
    for (int i = t; i < 1024; i += 256) {
        int g = i >> 6;
        shg[i] = hg_sum[i] / fmaxf((float)scnt[g], 1.f);
    }
    __syncthreads();
    if (t < 160) {
        int g = t / 10, c = t % 10;
        float acc = b_head[c];
#pragma unroll 16
        for (int k = 0; k < 64; ++k) acc = fmaf(shg[g * 64 + k], W_head[k * 10 + c], acc);
        slog[g * 10 + c] = acc;
    }
    __syncthreads();
    if (t < 16) {
        float mx = -INFINITY;
#pragma unroll
        for (int c = 0; c < 10; ++c) mx = fmaxf(mx, slog[t * 10 + c]);
        float e[10], s = 0.f;
#pragma unroll
        for (int c = 0; c < 10; ++c) { e[c] = __expf(slog[t * 10 + c] - mx); s += e[c]; }
        float inv = 1.f / s;
#pragma unroll
        for (int c = 0; c < 10; ++c) out[t * 10 + c] = e[c] * inv;
    }
}

extern "C" void kernel_launch(void* const* d_in, const int* in_sizes, int n_in,
                              void* d_out, int out_size, void* d_ws, size_t ws_size,
                              hipStream_t stream) {
    const float* g_feats  = (const float*)d_in[0];
    const int*   edge_src = (const int*)d_in[1];
    const int*   edge_dst = (const int*)d_in[2];
    const int*   gids     = (const int*)d_in[3];
    const float* W_in     = (const float*)d_in[4];
    const float* b_in     = (const float*)d_in[5];
    const float* W1       = (const float*)d_in[6];
    const float* attn_l1  = (const float*)d_in[7];
    const float* attn_r1  = (const float*)d_in[8];
    const float* bias1    = (const float*)d_in[9];
    const float* W2       = (const float*)d_in[10];
    const float* attn_l2  = (const float*)d_in[11];
    const float* attn_r2  = (const float*)d_in[12];
    const float* bias2    = (const float*)d_in[13];
    const float* W_head   = (const float*)d_in[14];
    const float* b_head   = (const float*)d_in[15];
    float* out = (float*)d_out;

    const int N = in_sizes[3];
    const int E = in_sizes[1];

    // workspace layout (16B-aligned sections)
    unsigned short* aggn = (unsigned short*)d_ws;             // N*512 bf16
    unsigned short* h0   = aggn + (size_t)N * 512;            // N*64 bf16
    unsigned short* h1   = h0 + (size_t)N * 64;               // N*64 bf16
    float* h2  = (float*)(h1 + (size_t)N * 64);               // N*64 f32
    float* hg  = h2 + (size_t)N * 64;                         // 16*64
    unsigned short* el = (unsigned short*)(hg + 16 * 64);     // N*8 bf16
    unsigned short* er = el + (size_t)N * 8;                  // N*8 bf16
    unsigned short* Bz1 = er + (size_t)N * 8;                 // 32768 bf16
    unsigned short* Bz2 = Bz1 + 32768;                        // 32768 bf16
    float* wl1 = (float*)(Bz2 + 32768);                       // 512 f32
    float* wr1 = wl1 + 512;
    float* wl2 = wr1 + 512;
    float* wr2 = wl2 + 512;
    float* biasm1 = wr2 + 512;                                // 64
    float* biasm2 = biasm1 + 64;                              // 64
    int* cnt        = (int*)(biasm2 + 64);                    // N
    int* row_start  = cnt + N;                                // N+1
    int* cursor     = row_start + N + 1;                      // N
    int* src_sorted = cursor + N;                             // E

    hipMemsetAsync(cnt, 0, (size_t)N * 4, stream);
    hipMemsetAsync(hg, 0, 16 * 64 * 4, stream);

    int eb = (E + 255) / 256;
    int nb4 = (N + 3) / 4;
    int nb32 = (N + 31) / 32;
    int nb256 = (N + 255) / 256;

    hist_kernel<<<eb, 256, 0, stream>>>(edge_dst, cnt, E);
    scan_kernel<<<1, 1024, 0, stream>>>(cnt, row_start, cursor, N);
    scatter_kernel<<<eb, 256, 0, stream>>>(edge_src, edge_dst, cursor, src_sorted, E);

    wprep_kernel<<<1, 256, 0, stream>>>(W1, attn_l1, attn_r1, bias1, wl1, wr1, biasm1);
    wprep_kernel<<<1, 256, 0, stream>>>(W2, attn_l2, attn_r2, bias2, wl2, wr2, biasm2);
    wswizB_kernel<<<16, 256, 0, stream>>>(W1, Bz1);
    wswizB_kernel<<<16, 256, 0, stream>>>(W2, Bz2);

    in_gemm<<<nb32, 256, 0, stream>>>(g_feats, W_in, b_in, wl1, wr1, h0, el, er, N);

    gat_h<<<nb4, 256, 0, stream>>>(h0, el, er, row_start, src_sorted, aggn, N);
    out_gemm<1><<<nb32, 256, 0, stream>>>(aggn, Bz1, biasm1, wl2, wr2, h1, nullptr, el, er, N);

    gat_h<<<nb4, 256, 0, stream>>>(h1, el, er, row_start, src_sorted, aggn, N);
    out_gemm<2><<<nb32, 256, 0, stream>>>(aggn, Bz2, biasm2, nullptr, nullptr, nullptr, h2, nullptr, nullptr, N);

    readout_partial<<<nb256, 256, 0, stream>>>(h2, gids, hg, N);
    head_kernel<<<1, 256, 0, stream>>>(hg, gids, W_head, b_head, out, N);
}